// Round 3
// baseline (1868.226 us; speedup 1.0000x reference)
//
#include <hip/hip_runtime.h>

#define NNODES 1000000
#define MDIM 128
#define MSGDIM 64
#define NE 16384
#define TWO_E 32768
#define GIN 352   // 2*MEM + MSG + TIME
#define GRROWS 16

typedef unsigned short u16;
typedef unsigned int u32;

// ---------------- all scratch as device globals: no d_ws dependence ----------------
__device__ u32   g_table[NNODES];            // 4 MB winner table
__device__ float g_hnew[(size_t)TWO_E * MDIM]; // 16 MB GRU outputs (fp32)
__device__ float g_Wr[GIN * MDIM];
__device__ float g_Wz[GIN * MDIM];
__device__ float g_Wi[GIN * MDIM];
__device__ float g_Wh[MDIM * MDIM];
__device__ float g_W1L[MDIM * MDIM];
__device__ float g_W1R[MDIM * MDIM];
__device__ int   g_isbf16;

__device__ __forceinline__ float bf2f(u16 u) {
  return __uint_as_float(((u32)u) << 16);
}
__device__ __forceinline__ u16 f2bf(float f) {
  u32 u = __float_as_uint(f);
  u += 0x7FFFu + ((u >> 16) & 1u);   // round-to-nearest-even
  return (u16)(u >> 16);
}
// dtype-adaptive input load: flag=1 -> bf16 stream, flag=0 -> fp32 stream
__device__ __forceinline__ float ldin(const void* p, size_t i, int f) {
  return f ? bf2f(((const u16*)p)[i]) : ((const float*)p)[i];
}

// ---------------- input dtype detector (runs every call; deterministic) ----------------
__global__ void k_detect(const void* probe) {
  if (blockIdx.x == 0 && threadIdx.x == 0) {
    const u16* p = (const u16*)probe;   // probe = memory table, values ~N(0,1)
    int cnt = 0;
    for (int i = 0; i < 64; ++i) {
      float a = fabsf(bf2f(p[i]));
      // genuine bf16 N(0,1): essentially all in [2^-10, 16); fp32-viewed-as-u16:
      // only the high halves (~32/64) land in range, low halves have wild exponents.
      if (a == 0.f || (a > 9.765625e-4f && a < 16.f)) ++cnt;
    }
    g_isbf16 = (cnt > 48) ? 1 : 0;
  }
}

// ---------------- winner table init (keeps the template's kernel name) ----------------
__global__ __launch_bounds__(256) void TGN_74861279969393_kernel() {
  int i = blockIdx.x * 256 + threadIdx.x;
  if (i < NNODES) g_table[i] = 0u;
}

// ---------------- weight prep: fuse + transpose to [k][d] fp32 ----------------
// g_Wr[k*128+d] = w_ih[d][k]      (+ w_hh[d][k], k<128)   -- r gate fused (x[0:128]==h)
// g_Wz[k*128+d] = w_ih[128+d][k]  (+ w_hh[128+d][k], k<128)
// g_Wi[k*128+d] = w_ih[256+d][k]
// g_Wh[k*128+d] = w_hh[256+d][k]  (k<128)                 -- n = tanh(i_n + r*h_n)
// g_W1L[c*128+j] = lp_w1[j][c],  g_W1R[c*128+j] = lp_w1[j][128+c]
__global__ __launch_bounds__(256) void k_prep(const void* w_ih, const void* w_hh,
                                              const void* lp_w1) {
  int f = g_isbf16;
  int i = blockIdx.x * 256 + threadIdx.x;
  const int SZ = GIN * MDIM;  // 45056
  if (i < 3 * SZ) {
    int seg = i / SZ, r = i - seg * SZ;
    int k = r >> 7, d = r & 127;
    int row = seg * 128 + d;
    float v = ldin(w_ih, (size_t)row * GIN + k, f);
    if (seg < 2 && k < 128) v += ldin(w_hh, (size_t)row * 128 + k, f);
    float* dst = (seg == 0) ? g_Wr : ((seg == 1) ? g_Wz : g_Wi);
    dst[r] = v;
  } else {
    int j = i - 3 * SZ;
    if (j < 16384) {
      int k = j >> 7, d = j & 127;
      g_Wh[j] = ldin(w_hh, (size_t)(256 + d) * 128 + k, f);
    } else if (j < 32768) {
      int q = j - 16384; int c = q >> 7, jj = q & 127;
      g_W1L[q] = ldin(lp_w1, (size_t)jj * 256 + c, f);
    } else if (j < 49152) {
      int q = j - 32768; int c = q >> 7, jj = q & 127;
      g_W1R[q] = ldin(lp_w1, (size_t)jj * 256 + 128 + c, f);
    }
  }
}

// ---------------- LastAggregator: atomicMax of (t+1)<<15 | row ----------------
__global__ __launch_bounds__(256) void k_scatter(const int* __restrict__ srcv,
                                                 const int* __restrict__ dstv,
                                                 const int* __restrict__ tv) {
  int g = blockIdx.x * 256 + threadIdx.x;
  if (g >= TWO_E) return;
  int e = (g < NE) ? g : (g - NE);
  int node = (g < NE) ? srcv[e] : dstv[e];
  u32 key = (((u32)(tv[e] + 1)) << 15) | (u32)g;  // t<2^17, g<2^15: exact pack
  atomicMax(&g_table[node], key);
}

// ---------------- GRU over all 2E message rows ----------------
__global__ __launch_bounds__(256) void k_gru(
    const void* mem, const int* __restrict__ last_update,
    const int* __restrict__ srcv, const int* __restrict__ dstv,
    const int* __restrict__ tv, const void* raw_msg,
    const void* time_w, const void* time_b,
    const void* b_ih, const void* b_hh) {
  __shared__ float xs[GRROWS][GIN];  // 22.5 KB
  __shared__ int s_node[GRROWS], s_oth[GRROWS], s_e[GRROWS];
  __shared__ float s_dt[GRROWS];
  int f = g_isbf16;
  int tid = threadIdx.x;
  int g0 = blockIdx.x * GRROWS;
  if (tid < GRROWS) {
    int g = g0 + tid;
    int e = (g < NE) ? g : (g - NE);
    int a = (g < NE) ? srcv[e] : dstv[e];   // node being updated (h_old = mem[a])
    int b = (g < NE) ? dstv[e] : srcv[e];
    s_node[tid] = a; s_oth[tid] = b; s_e[tid] = e;
    s_dt[tid] = (float)(tv[e] - last_update[a]);
  }
  __syncthreads();
  // stage x = [mem[a], mem[b], raw_msg, cos(dt*w+b)] as fp32
  for (int j = tid; j < GRROWS * GIN; j += 256) {
    int row = j / GIN, c = j - row * GIN;
    float v;
    if (c < 128)      v = ldin(mem, (size_t)s_node[row] * MDIM + c, f);
    else if (c < 256) v = ldin(mem, (size_t)s_oth[row] * MDIM + (c - 128), f);
    else if (c < 320) v = ldin(raw_msg, (size_t)s_e[row] * MSGDIM + (c - 256), f);
    else {
      int k = c - 320;
      v = cosf(s_dt[row] * ldin(time_w, k, f) + ldin(time_b, k, f));
    }
    xs[row][c] = v;
  }
  __syncthreads();
  int d = tid & 127, rg = tid >> 7;
  int r0 = rg * 8;
  float ar[8], az[8], ai[8], ah[8];
  #pragma unroll
  for (int i = 0; i < 8; ++i) { ar[i] = 0.f; az[i] = 0.f; ai[i] = 0.f; ah[i] = 0.f; }
  // k < 128: r/z fused (x==h there), plus i_n and h_n
  for (int k = 0; k < 128; k += 4) {
    float4 xv[8];
    #pragma unroll
    for (int i = 0; i < 8; ++i) xv[i] = *(const float4*)&xs[r0 + i][k];
    #pragma unroll
    for (int kk = 0; kk < 4; ++kk) {
      int kc = k + kk;
      float wr = g_Wr[kc * 128 + d], wz = g_Wz[kc * 128 + d];
      float wi = g_Wi[kc * 128 + d], wh = g_Wh[kc * 128 + d];
      #pragma unroll
      for (int i = 0; i < 8; ++i) {
        float x = (kk == 0) ? xv[i].x : (kk == 1) ? xv[i].y : (kk == 2) ? xv[i].z : xv[i].w;
        ar[i] = fmaf(wr, x, ar[i]); az[i] = fmaf(wz, x, az[i]);
        ai[i] = fmaf(wi, x, ai[i]); ah[i] = fmaf(wh, x, ah[i]);
      }
    }
  }
  // k in [128,352): only w_ih terms
  for (int k = 128; k < GIN; k += 4) {
    float4 xv[8];
    #pragma unroll
    for (int i = 0; i < 8; ++i) xv[i] = *(const float4*)&xs[r0 + i][k];
    #pragma unroll
    for (int kk = 0; kk < 4; ++kk) {
      int kc = k + kk;
      float wr = g_Wr[kc * 128 + d], wz = g_Wz[kc * 128 + d], wi = g_Wi[kc * 128 + d];
      #pragma unroll
      for (int i = 0; i < 8; ++i) {
        float x = (kk == 0) ? xv[i].x : (kk == 1) ? xv[i].y : (kk == 2) ? xv[i].z : xv[i].w;
        ar[i] = fmaf(wr, x, ar[i]); az[i] = fmaf(wz, x, az[i]); ai[i] = fmaf(wi, x, ai[i]);
      }
    }
  }
  float br = ldin(b_ih, d, f) + ldin(b_hh, d, f);
  float bz = ldin(b_ih, 128 + d, f) + ldin(b_hh, 128 + d, f);
  float bi = ldin(b_ih, 256 + d, f);
  float bh = ldin(b_hh, 256 + d, f);
  #pragma unroll
  for (int i = 0; i < 8; ++i) {
    float rr = 1.f / (1.f + __expf(-(ar[i] + br)));
    float zz = 1.f / (1.f + __expf(-(az[i] + bz)));
    float nn = tanhf(ai[i] + bi + rr * (ah[i] + bh));
    float h = xs[r0 + i][d];   // h_old[d]
    g_hnew[(size_t)(g0 + r0 + i) * MDIM + d] = (1.f - zz) * nn + zz * h;
  }
}

// ---------------- link prediction (pos & neg share the src half) ----------------
__global__ __launch_bounds__(256) void k_linkpred(
    const void* mem, const int* __restrict__ srcv,
    const int* __restrict__ posv, const int* __restrict__ negv,
    const void* lp_b1, const void* lp_w2, const void* lp_b2,
    void* outp) {
  __shared__ float semb[48][MDIM];  // 16 edges x {src,pos,neg}
  __shared__ int s_hrow[48], s_nd[48];
  int f = g_isbf16;
  int tid = threadIdx.x;
  int e0 = blockIdx.x * 16;
  if (tid < 48) {
    int el = tid / 3, role = tid - el * 3;
    int e = e0 + el;
    int node = (role == 0) ? srcv[e] : ((role == 1) ? posv[e] : negv[e]);
    u32 k = g_table[node];
    s_nd[tid] = node;
    s_hrow[tid] = k ? (int)(k & 0x7FFFu) : -1;  // winner message row or -1
  }
  __syncthreads();
  for (int j = tid; j < 48 * MDIM; j += 256) {
    int er = j >> 7, c = j & 127;
    int hr = s_hrow[er];
    semb[er][c] = (hr >= 0) ? g_hnew[(size_t)hr * MDIM + c]
                            : ldin(mem, (size_t)s_nd[er] * MDIM + c, f);
  }
  __syncthreads();
  int wave = tid >> 6, lane = tid & 63;  // each wave: 4 edges; lane j handles dims j, j+64
  float ua0[4], ua1[4], vp0[4], vp1[4], vn0[4], vn1[4];
  #pragma unroll
  for (int i = 0; i < 4; ++i) { ua0[i]=0.f; ua1[i]=0.f; vp0[i]=0.f; vp1[i]=0.f; vn0[i]=0.f; vn1[i]=0.f; }
  for (int c = 0; c < 128; ++c) {
    float l0 = g_W1L[c * 128 + lane], l1 = g_W1L[c * 128 + 64 + lane];
    float q0 = g_W1R[c * 128 + lane], q1 = g_W1R[c * 128 + 64 + lane];
    #pragma unroll
    for (int i = 0; i < 4; ++i) {
      int base = (wave * 4 + i) * 3;
      float a = semb[base][c], p = semb[base + 1][c], n = semb[base + 2][c];
      ua0[i] = fmaf(l0, a, ua0[i]); ua1[i] = fmaf(l1, a, ua1[i]);
      vp0[i] = fmaf(q0, p, vp0[i]); vp1[i] = fmaf(q1, p, vp1[i]);
      vn0[i] = fmaf(q0, n, vn0[i]); vn1[i] = fmaf(q1, n, vn1[i]);
    }
  }
  float b1a = ldin(lp_b1, lane, f), b1b = ldin(lp_b1, 64 + lane, f);
  float w2a = ldin(lp_w2, lane, f), w2b = ldin(lp_w2, 64 + lane, f);
  float b2 = ldin(lp_b2, 0, f);
  #pragma unroll
  for (int i = 0; i < 4; ++i) {
    int e = e0 + wave * 4 + i;
    float hp0 = fmaxf(ua0[i] + vp0[i] + b1a, 0.f);
    float hp1 = fmaxf(ua1[i] + vp1[i] + b1b, 0.f);
    float hq0 = fmaxf(ua0[i] + vn0[i] + b1a, 0.f);
    float hq1 = fmaxf(ua1[i] + vn1[i] + b1b, 0.f);
    float sp = w2a * hp0 + w2b * hp1;
    float sn = w2a * hq0 + w2b * hq1;
    #pragma unroll
    for (int off = 32; off > 0; off >>= 1) {
      sp += __shfl_down(sp, off, 64);
      sn += __shfl_down(sn, off, 64);
    }
    if (lane == 0) {
      if (f) { ((u16*)outp)[e] = f2bf(sp + b2); ((u16*)outp)[NE + e] = f2bf(sn + b2); }
      else   { ((float*)outp)[e] = sp + b2;     ((float*)outp)[NE + e] = sn + b2; }
    }
  }
}

extern "C" __attribute__((visibility("default")))
void kernel_launch(void* const* d_in, const int* in_sizes, int n_in,
                   void* d_out, int out_size, void* d_ws, size_t ws_size,
                   hipStream_t stream) {
  (void)in_sizes; (void)n_in; (void)out_size; (void)d_ws; (void)ws_size;
  const void* mem        = d_in[0];
  const int* last_update = (const int*)d_in[1];
  const int* srcv        = (const int*)d_in[2];
  const int* posv        = (const int*)d_in[3];
  const int* negv        = (const int*)d_in[4];
  const int* tv          = (const int*)d_in[5];
  const void* raw_msg    = d_in[6];
  const void* time_w     = d_in[7];
  const void* time_b     = d_in[8];
  const void* gw_ih      = d_in[9];
  const void* gw_hh      = d_in[10];
  const void* gb_ih      = d_in[11];
  const void* gb_hh      = d_in[12];
  const void* lp_w1      = d_in[13];
  const void* lp_b1      = d_in[14];
  const void* lp_w2      = d_in[15];
  const void* lp_b2      = d_in[16];

  hipStream_t s = stream;
  k_detect<<<1, 64, 0, s>>>(mem);
  if (hipGetLastError() != hipSuccess) {     // passed stream unusable -> fall back
    s = 0;
    k_detect<<<1, 64, 0, s>>>(mem);
  }
  // diagnostic sentinel: bf16 3.0 pattern; overwritten by k_linkpred when alive
  hipMemsetAsync(d_out, 0x40, (size_t)TWO_E * sizeof(u16), s);
  TGN_74861279969393_kernel<<<(NNODES + 255) / 256, 256, 0, s>>>();
  k_prep<<<720, 256, 0, s>>>(gw_ih, gw_hh, lp_w1);
  k_scatter<<<TWO_E / 256, 256, 0, s>>>(srcv, posv, tv);
  k_gru<<<TWO_E / GRROWS, 256, 0, s>>>(mem, last_update, srcv, posv, tv, raw_msg,
                                       time_w, time_b, gb_ih, gb_hh);
  k_linkpred<<<NE / 16, 256, 0, s>>>(mem, srcv, posv, negv,
                                     lp_b1, lp_w2, lp_b2, d_out);
}